// Round 5
// baseline (32.180 us; speedup 1.0000x reference)
//
#include <hip/hip_runtime.h>

#define THREADS 256
#define NPMAX   256

// ---------------------------------------------------------------------------
// Prep kernel (1 block): per-particle constants at time_idx, ballot-compacted
// (deterministic, stable order) into global d_ws as float4 pairs:
//   pa = {px, py, pz, -log2(e)/(2 r^2)}
//   pb = {A*dx, A*dy, A*dz, 9 r^2}        A = w / (r^3 * 40000)
// Main kernel reads them with wave-uniform indices -> scalar s_load (SMEM),
// keeping the inner loop free of LDS traffic entirely.
// ---------------------------------------------------------------------------
__global__ __launch_bounds__(THREADS) void vortex_prep(
        const float* __restrict__ ppos,
        const float* __restrict__ pdir,
        const float* __restrict__ pint,
        const float* __restrict__ iraw,
        const float* __restrict__ rad,
        const int*   __restrict__ tmask,
        const int*   __restrict__ tidxp,
        int P, int T,
        float4* __restrict__ parts,
        int*    __restrict__ dcount) {
    __shared__ int wtot[THREADS / 64];
    const int tid  = threadIdx.x;
    const int lane = tid & 63;
    const int wid  = tid >> 6;
    const int t = *tidxp;

    bool active = false;
    float4 a, b;
    if (tid < P) {
        const int p = tid;
        float m  = (float)tmask[p * T + t];
        float cl = fminf(fmaxf(iraw[p], 0.0f), 10.0f);
        float w  = sqrtf(cl + 1e-8f) * pint[p * T + t] * m;
        float r  = fmaxf(0.2f * (0.5f * rad[p] + 1.0f), 0.0f);
        active   = (w != 0.0f) && (r > 0.0f);
        if (active) {
            const float* pp = ppos + (size_t)(p * T + t) * 3;
            const float* pd = pdir + (size_t)(p * T + t) * 3;
            float A = w / (r * r * r * 40000.0f);
            a = make_float4(pp[0], pp[1], pp[2], -1.442695040888963f / (2.0f * r * r));
            b = make_float4(A * pd[0], A * pd[1], A * pd[2], 9.0f * r * r);
        }
    }
    unsigned long long bm = __ballot(active);
    int pre = __popcll(bm & ((1ull << lane) - 1ull));
    if (lane == 0) wtot[wid] = __popcll(bm);
    __syncthreads();
    int off = 0, tot = 0;
    #pragma unroll
    for (int w2 = 0; w2 < THREADS / 64; ++w2) {
        int c = wtot[w2];
        if (w2 < wid) off += c;
        tot += c;
    }
    if (active) {
        int pos = off + pre;
        parts[2 * pos]     = a;
        parts[2 * pos + 1] = b;
    }
    if (tid == 0) *dcount = tot;
}

// ---------------------------------------------------------------------------
// Main kernel: 1 coord/thread, loop over compacted particles with uniform
// (scalar) loads from global. No LDS in the hot loop.
// ---------------------------------------------------------------------------
__global__ __launch_bounds__(THREADS) void vortex_main(
        const float*  __restrict__ coord,
        const float4* __restrict__ parts,
        const int*    __restrict__ dcount,
        float*        __restrict__ out,
        int N) {
    const int i0 = blockIdx.x * THREADS + threadIdx.x;
    const bool v0 = (i0 < N);
    float cx = 0.f, cy = 0.f, cz = 0.f;
    if (v0) { cx = coord[3 * i0]; cy = coord[3 * i0 + 1]; cz = coord[3 * i0 + 2]; }

    // force the trip count into an SGPR (uniform scalar branch)
    const int cnt = __builtin_amdgcn_readfirstlane(*dcount);

    float ax = 0.f, ay = 0.f, az = 0.f;
    #pragma unroll 4
    for (int p = 0; p < cnt; ++p) {
        // uniform index + const __restrict__ global pointer -> s_load (SMEM)
        const float4 pa = parts[2 * p];
        const float4 pb = parts[2 * p + 1];
        float lx = pa.x - cx, ly = pa.y - cy, lz = pa.z - cz;
        float d2 = fmaf(lx, lx, fmaf(ly, ly, lz * lz));
        float s  = __builtin_amdgcn_exp2f(d2 * pa.w) * __builtin_amdgcn_rsqf(d2);
        s = (d2 < pb.w) ? s : 0.0f;
        float crx = fmaf(ly, pb.z, -(lz * pb.y));
        float cry = fmaf(lz, pb.x, -(lx * pb.z));
        float crz = fmaf(lx, pb.y, -(ly * pb.x));
        ax = fmaf(s, crx, ax);
        ay = fmaf(s, cry, ay);
        az = fmaf(s, crz, az);
    }

    if (v0) { out[3 * i0] = ax; out[3 * i0 + 1] = ay; out[3 * i0 + 2] = az; }
}

extern "C" void kernel_launch(void* const* d_in, const int* in_sizes, int n_in,
                              void* d_out, int out_size, void* d_ws, size_t ws_size,
                              hipStream_t stream) {
    const float* coord = (const float*)d_in[0];
    const float* ppos  = (const float*)d_in[1];
    const float* pdir  = (const float*)d_in[2];
    const float* pint  = (const float*)d_in[3];
    const float* iraw  = (const float*)d_in[4];
    const float* rad   = (const float*)d_in[5];
    const int*   tmask = (const int*)d_in[6];
    const int*   tidx  = (const int*)d_in[7];
    float* out = (float*)d_out;

    const int N = in_sizes[0] / 3;        // 262144 coords
    const int P = in_sizes[4];            // 256 particles (intensity_raw is (P,1))
    const int T = in_sizes[3] / P;        // 8 time steps (particle_intensity is (P,T,1))

    float4* parts = (float4*)d_ws;
    int* dcount   = (int*)((char*)d_ws + (size_t)2 * NPMAX * sizeof(float4));

    hipLaunchKernelGGL(vortex_prep, dim3(1), dim3(THREADS), 0, stream,
                       ppos, pdir, pint, iraw, rad, tmask, tidx, P, T, parts, dcount);

    const int blocks = (N + THREADS - 1) / THREADS;
    hipLaunchKernelGGL(vortex_main, dim3(blocks), dim3(THREADS), 0, stream,
                       coord, parts, dcount, out, N);
}